// Round 10
// baseline (386.244 us; speedup 1.0000x reference)
//
#include <hip/hip_runtime.h>
#include <math.h>

#define NB 32
#define NS 8192
#define NC 64
#define NM 16
#define NL 4
#define NM2 32                 // 2*M (cos,sin interleaved)
#define TPOS 128               // positions per tile (2 per thread)
#define NT (NS/TPOS)           // 64 tiles per batch
// LDS tile: hs[c*128 + (pos ^ (c&31))], 64*128*4 B = 32768 B exactly
// -> 5 blocks/CU (5*32768 = 163840 = 160 KB). XOR swizzle is conflict-free
// for row reads (D: lanes=pos), column reads (G: lanes=c), and keeps
// pos+64 at +64 (xor touches only low 5 bits).

typedef float f16v __attribute__((ext_vector_type(16)));
typedef float f8v  __attribute__((ext_vector_type(8)));

static __device__ __forceinline__ f8v zero8() {
    f8v v;
    #pragma unroll
    for (int j = 0; j < 8; ++j) v[j] = 0.0f;
    return v;
}

// A&S 7.1.26 erf (|err|<2e-7) -> exact-form gelu, ~14 VALU ops, no branches.
static __device__ __forceinline__ float gelu_fast(float v) {
    float x  = v * 0.7071067811865475f;
    float ax = fabsf(x);
    float d  = fmaf(0.3275911f, ax, 1.0f);
    float t;
    asm("v_rcp_f32 %0, %1" : "=v"(t) : "v"(d));
    float p = t * fmaf(t, fmaf(t, fmaf(t, fmaf(t, 1.061405429f, -1.453152027f),
                                       1.421413741f), -0.284496736f),
                       0.254829592f);
    float e = __expf(-ax * ax);
    float erfv = fmaf(-p, e, 1.0f);
    erfv = copysignf(erfv, x);
    return 0.5f * v * (1.0f + erfv);
}

// Build trig table T[s][2m]=cos(2*pi*m*s/NS), T[s][2m+1]=sin(2*pi*m*s/NS)
__global__ void k_table(float* __restrict__ T) {
    int s = blockIdx.x * blockDim.x + threadIdx.x;
    if (s >= NS) return;
    const float w = 6.283185307179586f / (float)NS;
    float* row = T + (size_t)s * NM2;
    #pragma unroll
    for (int m = 0; m < NM; ++m) {
        int idx = (m * s) & (NS - 1);
        float a = w * (float)idx;
        float sv, cv;
        sincosf(a, &sv, &cv);
        row[2*m]   = cv;
        row[2*m+1] = sv;
    }
}

// Transpose Wl_w [L][o][i] -> Wt [L][i][o]; d1_w [o][i] -> d1t [i][o]
__global__ void k_prep(const float* __restrict__ Ww, const float* __restrict__ d1w,
                       float* __restrict__ Wt, float* __restrict__ d1t) {
    int idx = blockIdx.x * 256 + threadIdx.x;
    if (idx < NL*NC*NC) {
        int l = idx / (NC*NC), r = idx % (NC*NC);
        int i = r / NC, o = r % NC;
        Wt[idx] = Ww[(size_t)l*NC*NC + (size_t)o*NC + i];
    } else if (idx < NL*NC*NC + NC*NC) {
        int r = idx - NL*NC*NC;
        int i = r / NC, o = r % NC;
        d1t[r] = d1w[(size_t)o*NC + i];
    }
}

// Shared DFT phase: swizzled hs; computes partial[c][k] for the wave's 8
// modes; trig rows are wave-uniform s_loads.
static __device__ __forceinline__ void dft_phase(
        const float* __restrict__ hs, const float* __restrict__ T,
        float* __restrict__ partial, int b, int tile, int s0,
        int og, int t) {
    int c = t & 63;
    int cm = c & 31;
    const float* hrow = hs + c * TPOS;
    f8v acc = zero8();
    const float* trow = T + (size_t)s0 * NM2 + og * 8;
    #pragma unroll 4
    for (int ss = 0; ss < TPOS; ++ss) {
        float hv = hrow[ss ^ cm];
        f8v tv = *(const f8v*)(trow + (size_t)ss * NM2);
        acc += hv * tv;
    }
    float* pout = partial + (((size_t)b*NT + tile)*NC + c)*NM2 + og*8;
    *(f8v*)pout = acc;
}

// Encoder fused with layer-0 forward DFT. Block = one 128-position tile.
__global__ void __launch_bounds__(256) k_enc(const float* __restrict__ x,
                                             const float* __restrict__ ew,
                                             const float* __restrict__ eb,
                                             const float* __restrict__ T,
                                             float* __restrict__ h,
                                             float* __restrict__ partial) {
    __shared__ float hs[NC * TPOS];   // 32 KB
    int tile = blockIdx.x, b = blockIdx.y;
    int t = threadIdx.x;
    int og = __builtin_amdgcn_readfirstlane(t >> 6);
    int p  = t & 63;
    int s0 = tile * TPOS;

    float xA = x[(size_t)b*NS + s0 + p];
    float xB = x[(size_t)b*NS + s0 + p + 64];
    f16v ew16 = *(const f16v*)(ew + og*16);
    f16v eb16 = *(const f16v*)(eb + og*16);
    f16v hA = xA * ew16 + eb16;
    f16v hB = xB * ew16 + eb16;

    *(f16v*)(h + ((size_t)b*NS + s0 + p)*NC + og*16)      = hA;
    *(f16v*)(h + ((size_t)b*NS + s0 + p + 64)*NC + og*16) = hB;

    #pragma unroll
    for (int j = 0; j < 16; ++j) {
        int c = og*16 + j;
        int off = p ^ (c & 31);
        hs[c*TPOS + off]      = hA[j];
        hs[c*TPOS + off + 64] = hB[j];
    }
    __syncthreads();

    dft_phase(hs, T, partial, b, tile, s0, og, t);
}

// Reduce tile partials -> xf columns (this block's 8 k's), apply complex R
// mixing, pre-scale for inverse. grid (NB, 4).
__global__ void __launch_bounds__(256) k_mix(const float* __restrict__ partial,
                                             const float* __restrict__ Rre,
                                             const float* __restrict__ Rim,
                                             float* __restrict__ yst, int l) {
    __shared__ float xf[NC * 8];   // 2 KB: [c][kk], k = 8*jg + kk
    int b = blockIdx.x, jg = blockIdx.y, t = threadIdx.x;
    #pragma unroll
    for (int e = 0; e < 2; ++e) {
        int idx = t + 256*e;               // 0..511 = c*8 + kk
        int c = idx >> 3, kk = idx & 7;
        const float* pp = partial + (size_t)b*NT*NC*NM2 + (size_t)c*NM2 + 8*jg + kk;
        float s = 0.f;
        #pragma unroll 8
        for (int tile = 0; tile < NT; ++tile)
            s += pp[(size_t)tile * NC * NM2];
        xf[idx] = s;
    }
    __syncthreads();
    {
        int o = t >> 2, mq = t & 3;
        int m = 4*jg + mq;
        float yre = 0.f, yim = 0.f;
        #pragma unroll 8
        for (int i = 0; i < NC; ++i) {
            float xr = xf[i*8 + 2*mq];
            float xs = xf[i*8 + 2*mq + 1];
            size_t ridx = (((size_t)l*NC + i)*NC + o)*NM + m;
            float rr = Rre[ridx], ri = Rim[ridx];
            yre = fmaf(xr, rr, yre); yre = fmaf(xs, ri, yre);
            yim = fmaf(xr, ri, yim); yim = fmaf(-xs, rr, yim);
        }
        float* yb = yst + (size_t)b*NM2*NC;
        if (m == 0) { yb[o] = yre * (1.0f/NS); yb[NC + o] = 0.f; }
        else {
            yb[(size_t)(2*m)*NC + o]   = yre * (2.0f/NS);
            yb[(size_t)(2*m+1)*NC + o] = -yim * (2.0f/NS);
        }
    }
}

// Fused spectral + Wl + GELU (+ next-layer DFT, or decoder when LAST).
template<bool LAST>
__global__ void __launch_bounds__(256) k_spec(float* __restrict__ h,
                                              const float* __restrict__ T,
                                              const float* __restrict__ yst,
                                              const float* __restrict__ Wt,
                                              const float* __restrict__ Wb,
                                              const float* __restrict__ d1t,
                                              const float* __restrict__ d1b,
                                              const float* __restrict__ d2w,
                                              const float* __restrict__ d2b,
                                              float* __restrict__ partial,
                                              float* __restrict__ outp,
                                              int l) {
    __shared__ float hs[NC * TPOS];   // 32 KB exactly -> 5 blocks/CU
    int tile = blockIdx.x, b = blockIdx.y;
    int t = threadIdx.x;
    int og = __builtin_amdgcn_readfirstlane(t >> 6);
    int p  = t & 63;
    int s0 = tile * TPOS;

    // A: issue coalesced tile loads
    const float4* hblk = (const float4*)(h + ((size_t)b*NS + s0)*NC);
    float4 ld0 = hblk[t];
    float4 ld1 = hblk[t + 256];
    float4 ld2 = hblk[t + 512];
    float4 ld3 = hblk[t + 768];
    float4 ld4 = hblk[t + 1024];
    float4 ld5 = hblk[t + 1280];
    float4 ld6 = hblk[t + 1536];
    float4 ld7 = hblk[t + 1792];

    const float* Wl = Wt + (size_t)l*NC*NC + og*16;    // [i][og*16..)
    const float* bl = Wb + (size_t)l*NC + og*16;
    const float* yb = yst + (size_t)b*NM2*NC + og*16;  // [k][og*16..)

    f16v accA = *(const f16v*)bl;
    f16v accB = accA;

    // B: spectral (overlaps global-load latency); native trig, B-position
    // trig derived from A by a constant rotation of 64/NS revolutions.
    {
        f16v y0 = *(const f16v*)yb;        // m=0 cos row (sin row is zero)
        accA += y0;
        accB += y0;
        float rev = (float)(s0 + p) * (1.0f / (float)NS);   // exact
        float cA1, sA1;
        asm("v_cos_f32 %0, %1" : "=v"(cA1) : "v"(rev));
        asm("v_sin_f32 %0, %1" : "=v"(sA1) : "v"(rev));
        const float cd = 0.99879545620517239f;   // cos(2*pi*64/8192)
        const float sd = 0.04906767432741802f;   // sin(2*pi*64/8192)
        float cB1 = cA1*cd - sA1*sd;
        float sB1 = sA1*cd + cA1*sd;
        float cmA = cA1, smA = sA1, cmB = cB1, smB = sB1;
        #pragma unroll 1
        for (int m = 1; m < NM; ++m) {
            f16v yc  = *(const f16v*)(yb + (size_t)(2*m)*NC);
            f16v ysv = *(const f16v*)(yb + (size_t)(2*m+1)*NC);
            accA += cmA * yc;  accA += smA * ysv;
            accB += cmB * yc;  accB += smB * ysv;
            float cnA = cmA*cA1 - smA*sA1;
            smA = cmA*sA1 + smA*cA1;  cmA = cnA;
            float cnB = cmB*cB1 - smB*sB1;
            smB = cmB*sB1 + smB*cB1;  cmB = cnB;
        }
    }

    // C: stage old h into swizzled LDS
    {
        float4 lds[8] = {ld0, ld1, ld2, ld3, ld4, ld5, ld6, ld7};
        #pragma unroll
        for (int jj = 0; jj < 8; ++jj) {
            int idx = t + 256*jj;          // float4 index: pos=idx>>4, q=idx&15
            int pos = idx >> 4;
            int cbase = (idx & 15) * 4;
            float vals[4] = {lds[jj].x, lds[jj].y, lds[jj].z, lds[jj].w};
            #pragma unroll
            for (int j2 = 0; j2 < 4; ++j2) {
                int c = cbase + j2;
                hs[c*TPOS + (pos ^ (c & 31))] = vals[j2];
            }
        }
    }
    __syncthreads();

    // D: dense from LDS, W rows shared by both accumulators
    #pragma unroll 8
    for (int i = 0; i < NC; ++i) {
        int off = p ^ (i & 31);
        float va = hs[i*TPOS + off];
        float vb = hs[i*TPOS + off + 64];
        f16v w = *(const f16v*)(Wl + (size_t)i*NC);
        accA += va * w;
        accB += vb * w;
    }

    // E: gelu (+ global h write unless LAST)
    f16v gA, gB;
    #pragma unroll
    for (int j = 0; j < 16; ++j) gA[j] = gelu_fast(accA[j]);
    #pragma unroll
    for (int j = 0; j < 16; ++j) gB[j] = gelu_fast(accB[j]);
    if (!LAST) {
        *(f16v*)(h + ((size_t)b*NS + s0 + p)*NC + og*16)      = gA;
        *(f16v*)(h + ((size_t)b*NS + s0 + p + 64)*NC + og*16) = gB;
    }

    // F: overwrite LDS with g (all dense reads complete first)
    __syncthreads();
    #pragma unroll
    for (int j = 0; j < 16; ++j) {
        int c = og*16 + j;
        int off = p ^ (c & 31);
        hs[c*TPOS + off]      = gA[j];
        hs[c*TPOS + off + 64] = gB[j];
    }
    __syncthreads();

    if (!LAST) {
        // G: forward DFT of the new h tile for the next layer
        dft_phase(hs, T, partial, b, tile, s0, og, t);
    } else {
        // G': decoder from LDS -> out; reduction reuses hs after a barrier
        f16v aA = *(const f16v*)(d1b + og*16);
        f16v aB = aA;
        #pragma unroll 8
        for (int i = 0; i < NC; ++i) {
            int off = p ^ (i & 31);
            float va = hs[i*TPOS + off];
            float vb = hs[i*TPOS + off + 64];
            f16v w = *(const f16v*)(d1t + (size_t)i*NC + og*16);
            aA += va * w;
            aB += vb * w;
        }
        float resA = 0.f, resB = 0.f;
        #pragma unroll
        for (int j = 0; j < 16; ++j) {
            float dw = d2w[og*16 + j];
            resA = fmaf(gelu_fast(aA[j]), dw, resA);
            resB = fmaf(gelu_fast(aB[j]), dw, resB);
        }
        __syncthreads();
        hs[og*TPOS + p]      = resA;
        hs[og*TPOS + p + 64] = resB;
        __syncthreads();
        if (t < TPOS) {
            outp[(size_t)b*NS + s0 + t] = d2b[0] + hs[t] + hs[TPOS + t]
                                        + hs[2*TPOS + t] + hs[3*TPOS + t];
        }
    }
}

extern "C" void kernel_launch(void* const* d_in, const int* in_sizes, int n_in,
                              void* d_out, int out_size, void* d_ws, size_t ws_size,
                              hipStream_t stream) {
    const float* input = (const float*)d_in[0];
    const float* enc_w = (const float*)d_in[1];
    const float* enc_b = (const float*)d_in[2];
    const float* R_re  = (const float*)d_in[3];
    const float* R_im  = (const float*)d_in[4];
    const float* Wl_w  = (const float*)d_in[5];
    const float* Wl_b  = (const float*)d_in[6];
    const float* d1_w  = (const float*)d_in[7];
    const float* d1_b  = (const float*)d_in[8];
    const float* d2_w  = (const float*)d_in[9];
    const float* d2_b  = (const float*)d_in[10];
    float* out = (float*)d_out;

    float* ws  = (float*)d_ws;
    float* h   = ws;                               // NB*NS*NC = 16.78M floats
    float* T   = h   + (size_t)NB*NS*NC;           // NS*NM2 = 262144
    float* par = T   + (size_t)NS*NM2;             // NB*NT*NC*NM2 = 4.19M
    float* yst = par + (size_t)NB*NT*NC*NM2;       // NB*NM2*NC = 65536
    float* Wt  = yst + (size_t)NB*NM2*NC;          // NL*NC*NC = 16384
    float* d1t = Wt  + (size_t)NL*NC*NC;           // NC*NC = 4096

    hipLaunchKernelGGL(k_table, dim3(NS/256), dim3(256), 0, stream, T);
    hipLaunchKernelGGL(k_prep, dim3((NL*NC*NC + NC*NC + 255)/256), dim3(256), 0,
                       stream, Wl_w, d1_w, Wt, d1t);
    hipLaunchKernelGGL(k_enc, dim3(NT, NB), dim3(256), 0, stream,
                       input, enc_w, enc_b, T, h, par);
    for (int l = 0; l < NL; ++l) {
        hipLaunchKernelGGL(k_mix, dim3(NB, 4), dim3(256), 0, stream,
                           par, R_re, R_im, yst, l);
        if (l < NL - 1) {
            hipLaunchKernelGGL((k_spec<false>), dim3(NT, NB), dim3(256), 0, stream,
                               h, T, yst, Wt, Wl_b, d1t, d1_b, d2_w, d2_b,
                               par, out, l);
        } else {
            hipLaunchKernelGGL((k_spec<true>), dim3(NT, NB), dim3(256), 0, stream,
                               h, T, yst, Wt, Wl_b, d1t, d1_b, d2_w, d2_b,
                               par, out, l);
        }
    }
}